// Round 1
// baseline (217.975 us; speedup 1.0000x reference)
//
#include <hip/hip_runtime.h>

// Problem constants
#define WF 512
#define HF 256
#define CF 64
#define NDTOT 65

static constexpr size_t CH  = (size_t)HF * WF;   // one channel plane (elements)
static constexpr size_t WH  = (size_t)HF * WF;   // one (b,d) output plane (elements)
static constexpr float  INV = 1.0f / 576.0f;     // 1/(K*K*C)

// ---------------------------------------------------------------------------
// k1: per (b, y) row — compute horizontally box-summed channel-dot rows
//     r[d][x] = sum_{v=x-1..x+1} sum_c x0[b,c,y,v] * x1[b,c,y,v+d-32]
// for d in [D0, D1), written to ws[dd][y][x] (dd = d - D0).
// Block: 256 threads; thread t owns columns 2t and 2t+1.
// ---------------------------------------------------------------------------
template<int D0, int D1>
__global__ __launch_bounds__(256, 2)
void corr_rows(const float* __restrict__ x0, const float* __restrict__ x1,
               float* __restrict__ ws, size_t wsBStride) {
    constexpr int ND = D1 - D0;
    const int y = blockIdx.x;
    const int b = blockIdx.y;
    const int t = threadIdx.x;

    // lds1[i] holds x1 column (i-32) of the current channel row; OOB -> 0.
    __shared__ __align__(16) float lds1[576];
    __shared__ float edgeO[4][ND];  // per-wave lane-63 acc_o (left edge for next wave)
    __shared__ float edgeE[4][ND];  // per-wave lane-0  acc_e (right edge for prev wave)

    const float* x0row = x0 + (size_t)b * CF * CH + (size_t)y * WF;
    const float* x1row = x1 + (size_t)b * CF * CH + (size_t)y * WF;

    float acc_e[ND], acc_o[ND];
#pragma unroll
    for (int i = 0; i < ND; ++i) { acc_e[i] = 0.f; acc_o[i] = 0.f; }

    // staging columns for lds indices t, t+256, t+512
    const int c0 = t - 32;        // in [-32, 223]
    const int c1 = t + 224;       // in [224, 479] : always valid
    const int c2 = t + 480;       // in [480, 543] : valid iff < 512 (t < 32)

    // prefetch channel 0
    float v0 = (c0 >= 0) ? x1row[c0] : 0.f;
    float v1 = x1row[c1];
    float v2 = (t < 64 && c2 < WF) ? x1row[c2] : 0.f;
    float2 x0v = *(const float2*)(x0row + 2 * t);

    for (int c = 0; c < CF; ++c) {
        __syncthreads();                      // prior readers done
        lds1[t]       = v0;
        lds1[t + 256] = v1;
        if (t < 64) lds1[t + 512] = v2;
        __syncthreads();                      // row c staged

        const float2 x0cur = x0v;
        if (c + 1 < CF) {                     // prefetch next channel (latency hidden by d-loop)
            const float* xr = x1row + (size_t)(c + 1) * CH;
            v0 = (c0 >= 0) ? xr[c0] : 0.f;
            v1 = xr[c1];
            v2 = (t < 64 && c2 < WF) ? xr[c2] : 0.f;
            x0v = *(const float2*)(x0row + (size_t)(c + 1) * CH + 2 * t);
        }

        const float2* f2 = (const float2*)lds1;   // f2[k] = {lds1[2k], lds1[2k+1]}
        float2 nxt = f2[t + D0 / 2];
#pragma unroll
        for (int j = D0 / 2; j < D1 / 2; ++j) {   // d = 2j, 2j+1
            const float2 cur = nxt;
            nxt = f2[t + j + 1];
            const int dd = 2 * j - D0;
            acc_e[dd]     += x0cur.x * cur.x;     // lds1[2t + d]
            acc_e[dd + 1] += x0cur.x * cur.y;
            acc_o[dd]     += x0cur.y * cur.y;     // lds1[2t+1 + d]
            acc_o[dd + 1] += x0cur.y * nxt.x;
        }
        if constexpr (D1 & 1) {                   // tail d = D1-1 (even)
            acc_e[ND - 1] += x0cur.x * nxt.x;
            acc_o[ND - 1] += x0cur.y * nxt.y;
        }
    }

    // horizontal 3-sum: r[2t] = accO(t-1) + acc_e + acc_o ; r[2t+1] = acc_e + acc_o + accE(t+1)
    const int wv = t >> 6, ln = t & 63;
    if (ln == 63) {
#pragma unroll
        for (int dd = 0; dd < ND; ++dd) edgeO[wv][dd] = acc_o[dd];
    }
    if (ln == 0) {
#pragma unroll
        for (int dd = 0; dd < ND; ++dd) edgeE[wv][dd] = acc_e[dd];
    }
    __syncthreads();

    float* wsb = ws + (size_t)b * wsBStride;
#pragma unroll
    for (int dd = 0; dd < ND; ++dd) {
        float lo = __shfl_up(acc_o[dd], 1);
        if (ln == 0) lo = (wv == 0) ? 0.f : edgeO[wv - 1][dd];
        float re = __shfl_down(acc_e[dd], 1);
        if (ln == 63) re = (wv == 3) ? 0.f : edgeE[wv + 1][dd];
        const float s = acc_e[dd] + acc_o[dd];
        float2 o2;
        o2.x = lo + s;
        o2.y = s + re;
        *(float2*)(wsb + ((size_t)dd * HF + y) * WF + 2 * t) = o2;
    }
}

// ---------------------------------------------------------------------------
// k2: vertical 3-sum + scale: out[d][i][j] = INV * (r[i-1] + r[i] + r[i+1])
// grid: (8 rowgroups, DC, nb); block 256 = 2 chains x 128 float4-columns.
// ---------------------------------------------------------------------------
__global__ __launch_bounds__(256)
void corr_vsum(const float* __restrict__ ws, float* __restrict__ out,
               size_t wsBStride, size_t outBStride) {
    const int t = threadIdx.x;
    const int chain = t >> 7;             // 0,1
    const int j = (t & 127) * 4;
    const int r0 = blockIdx.x * 32 + chain * 16;
    const int d = blockIdx.y;
    const int b = blockIdx.z;

    const float* wp = ws + (size_t)b * wsBStride + (size_t)d * WH + j;
    float* op       = out + (size_t)b * outBStride + (size_t)d * WH + j;

    float4 prev, cur;
    if (r0 > 0) prev = *(const float4*)(wp + (size_t)(r0 - 1) * WF);
    else        prev = make_float4(0.f, 0.f, 0.f, 0.f);
    cur = *(const float4*)(wp + (size_t)r0 * WF);

#pragma unroll
    for (int i = 0; i < 16; ++i) {
        const int r = r0 + i;
        float4 nx;
        if (r + 1 < HF) nx = *(const float4*)(wp + (size_t)(r + 1) * WF);
        else            nx = make_float4(0.f, 0.f, 0.f, 0.f);
        float4 o;
        o.x = (prev.x + cur.x + nx.x) * INV;
        o.y = (prev.y + cur.y + nx.y) * INV;
        o.z = (prev.z + cur.z + nx.z) * INV;
        o.w = (prev.w + cur.w + nx.w) * INV;
        *(float4*)(op + (size_t)r * WF) = o;
        prev = cur; cur = nx;
    }
}

// ---------------------------------------------------------------------------
// Emergency fallback (tiny ws): direct computation, slow but correct.
// ---------------------------------------------------------------------------
__global__ void corr_naive(const float* __restrict__ x0, const float* __restrict__ x1,
                           float* __restrict__ out) {
    const size_t total = (size_t)4 * NDTOT * WH;
    size_t idx = (size_t)blockIdx.x * blockDim.x + threadIdx.x;
    if (idx >= total) return;
    const int j = (int)(idx % WF);
    const int i = (int)((idx / WF) % HF);
    const int d = (int)((idx / WH) % NDTOT);
    const int b = (int)(idx / ((size_t)NDTOT * WH));
    const int disp = d - 32;
    float s = 0.f;
    for (int u = i - 1; u <= i + 1; ++u) {
        if (u < 0 || u >= HF) continue;
        for (int v = j - 1; v <= j + 1; ++v) {
            if (v < 0 || v >= WF) continue;
            const int v1c = v + disp;
            if (v1c < 0 || v1c >= WF) continue;
            const float* p0 = x0 + (size_t)b * CF * CH + (size_t)u * WF + v;
            const float* p1 = x1 + (size_t)b * CF * CH + (size_t)u * WF + v1c;
            for (int c = 0; c < CF; ++c)
                s += p0[(size_t)c * CH] * p1[(size_t)c * CH];
        }
    }
    out[idx] = s * INV;
}

// ---------------------------------------------------------------------------
extern "C" void kernel_launch(void* const* d_in, const int* in_sizes, int n_in,
                              void* d_out, int out_size, void* d_ws, size_t ws_size,
                              hipStream_t stream) {
    const float* x0 = (const float*)d_in[0];
    const float* x1 = (const float*)d_in[1];
    float* out = (float*)d_out;
    float* ws  = (float*)d_ws;

    const size_t fullB = (size_t)NDTOT * WH;     // per-b ws elements, full d range

    if (ws_size >= 4 * fullB * sizeof(float)) {
        // Full pipeline: one k1 + one k2
        corr_rows<0, 65><<<dim3(256, 4), dim3(256), 0, stream>>>(x0, x1, ws, fullB);
        corr_vsum<<<dim3(8, 65, 4), dim3(256), 0, stream>>>(ws, out, fullB, fullB);
    } else if (ws_size >= fullB * sizeof(float)) {
        // Per-batch chunks
        for (int b = 0; b < 4; ++b) {
            const float* x0b = x0 + (size_t)b * CF * CH;
            const float* x1b = x1 + (size_t)b * CF * CH;
            float* outb = out + (size_t)b * fullB;
            corr_rows<0, 65><<<dim3(256, 1), dim3(256), 0, stream>>>(x0b, x1b, ws, 0);
            corr_vsum<<<dim3(8, 65, 1), dim3(256), 0, stream>>>(ws, outb, 0, 0);
        }
    } else if (ws_size >= 33 * WH * sizeof(float)) {
        // Per-batch, d split in halves
        for (int b = 0; b < 4; ++b) {
            const float* x0b = x0 + (size_t)b * CF * CH;
            const float* x1b = x1 + (size_t)b * CF * CH;
            float* outb = out + (size_t)b * fullB;
            corr_rows<0, 32><<<dim3(256, 1), dim3(256), 0, stream>>>(x0b, x1b, ws, 0);
            corr_vsum<<<dim3(8, 32, 1), dim3(256), 0, stream>>>(ws, outb, 0, 0);
            corr_rows<32, 65><<<dim3(256, 1), dim3(256), 0, stream>>>(x0b, x1b, ws, 0);
            corr_vsum<<<dim3(8, 33, 1), dim3(256), 0, stream>>>(ws, outb + (size_t)32 * WH, 0, 0);
        }
    } else {
        // Tiny ws: direct fallback
        const size_t total = (size_t)4 * NDTOT * WH;
        const int blocks = (int)((total + 255) / 256);
        corr_naive<<<dim3(blocks), dim3(256), 0, stream>>>(x0, x1, out);
    }
}